// Round 1
// baseline (3739.244 us; speedup 1.0000x reference)
//
#include <hip/hip_runtime.h>
#include <math.h>

#define HID 128
constexpr int Nn = 20000;
constexpr int Ee = 80000;
constexpr int Gg = 1000;

__device__ __forceinline__ float eluf(float x){ return x > 0.f ? x : (expf(x) - 1.f); }

// h0 = x[:, :5]
__global__ void h0_kernel(const float* __restrict__ x, float* __restrict__ h){
  int idx = blockIdx.x * blockDim.x + threadIdx.x;
  if (idx >= Nn * 5) return;
  int n = idx / 5, c = idx - n * 5;
  h[idx] = x[(size_t)n * 16 + c];
}

// w2t[io*128 + k] = w2[k*iotot + io]
__global__ void w2t_kernel(const float* __restrict__ w2, float* __restrict__ w2t, int iotot){
  int idx = blockIdx.x * blockDim.x + threadIdx.x;
  if (idx >= iotot * HID) return;
  int io = idx >> 7, k = idx & 127;
  w2t[idx] = w2[(size_t)k * iotot + io];
}

// agg[n,o] = bias[o] + sum_i h[n,i]*root[i,o]
template<int MI, int MO>
__global__ void node_kernel(const float* __restrict__ h, const float* __restrict__ root,
                            const float* __restrict__ bias, float* __restrict__ agg){
  int idx = blockIdx.x * blockDim.x + threadIdx.x;
  if (idx >= Nn * MO) return;
  int n = idx / MO, o = idx - n * MO;
  float s = bias[o];
  #pragma unroll
  for (int i = 0; i < MI; ++i) s += h[(size_t)n * MI + i] * root[i * MO + o];
  agg[idx] = s;
}

// agg[dst[e],o] += sum_i h[src[e],i] * ( dot(hid[e], w2[:, i*MO+o]) + b2[i*MO+o] )
// hid[e,k] = relu(edge_attr[e] @ w1 + b1)[k], computed in-LDS per tile.
template<int MI, int MO>
__global__ __launch_bounds__(256) void edge_kernel(
    const float* __restrict__ ea, const float* __restrict__ w1, const float* __restrict__ b1,
    const float* __restrict__ w2t, const float* __restrict__ b2,
    const float* __restrict__ h, const int* __restrict__ src, const int* __restrict__ dst,
    float* __restrict__ agg)
{
  constexpr int TE = 64;
  constexpr int OW = MO / 4;      // columns per wave (4 waves)
  __shared__ float ea_lds[TE * 5];
  __shared__ __align__(16) float hid_lds[TE][132];   // pad 132: 528B row, 16B aligned
  __shared__ float hs_lds[TE][MI + 1];

  const int tid  = threadIdx.x;
  const int lane = tid & 63;
  const int wave = tid >> 6;
  const int e0   = blockIdx.x * TE;

  for (int t = tid; t < TE * 5; t += 256) ea_lds[t] = ea[(size_t)e0 * 5 + t];
  for (int t = tid; t < TE * MI; t += 256){
    int le = t / MI, i = t - le * MI;
    hs_lds[le][i] = h[(size_t)src[e0 + le] * MI + i];
  }
  __syncthreads();
  for (int t = tid; t < TE * HID; t += 256){
    int le = t >> 7, k = t & 127;
    float s = b1[k];
    #pragma unroll
    for (int j = 0; j < 5; ++j) s += ea_lds[le * 5 + j] * w1[j * HID + k];
    hid_lds[le][k] = fmaxf(s, 0.f);
  }
  __syncthreads();

  const int e  = e0 + lane;
  const int O0 = __builtin_amdgcn_readfirstlane(wave * OW);
  const int d  = dst[e];
  const float4* __restrict__ w2t4 = (const float4*)w2t;

  float acc[OW];
  #pragma unroll
  for (int ow = 0; ow < OW; ++ow) acc[ow] = 0.f;

  // b2 bias term
  for (int i = 0; i < MI; ++i){
    float hs = hs_lds[lane][i];
    #pragma unroll
    for (int ow = 0; ow < OW; ++ow) acc[ow] += hs * b2[i * MO + O0 + ow];
  }

  for (int kb = 0; kb < HID / 4; ++kb){
    float4 hv = *(const float4*)&hid_lds[lane][kb * 4];
    for (int i = 0; i < MI; ++i){
      float hs  = hs_lds[lane][i];
      float hwx = hs * hv.x, hwy = hs * hv.y, hwz = hs * hv.z, hww = hs * hv.w;
      #pragma unroll
      for (int ow = 0; ow < OW; ++ow){
        float4 wv = w2t4[(size_t)(i * MO + O0 + ow) * (HID / 4) + kb];
        acc[ow] += hwx * wv.x + hwy * wv.y + hwz * wv.z + hww * wv.w;
      }
    }
  }
  #pragma unroll
  for (int ow = 0; ow < OW; ++ow)
    atomicAdd(&agg[(size_t)d * MO + O0 + ow], acc[ow]);
}

__global__ void elu_kernel(const float* __restrict__ agg, float* __restrict__ h, int n){
  int i = blockIdx.x * blockDim.x + threadIdx.x;
  if (i < n) h[i] = eluf(agg[i]);
}

__global__ void zero_kernel(float* __restrict__ p, int n){
  int i = blockIdx.x * blockDim.x + threadIdx.x;
  if (i < n) p[i] = 0.f;
}

// sums[batch[n], f] += hcat[n,f]; cnts[batch[n]] += 1
__global__ void pool_kernel(const float* __restrict__ h, const float* __restrict__ x,
                            const int* __restrict__ batch,
                            float* __restrict__ sums, float* __restrict__ cnts){
  int idx = blockIdx.x * blockDim.x + threadIdx.x;
  if (idx >= Nn * 75) return;
  int n = idx / 75, f = idx - n * 75;
  float v = (f < 64) ? h[(size_t)n * 64 + f] : x[(size_t)n * 16 + 5 + (f - 64)];
  int b = batch[n];
  atomicAdd(&sums[(size_t)b * 75 + f], v);
  if (f == 0) atomicAdd(&cnts[b], 1.f);
}

__global__ __launch_bounds__(64) void head_kernel(
    const float* __restrict__ sums, const float* __restrict__ cnts,
    const float* __restrict__ fc1w, const float* __restrict__ fc1b,
    const float* __restrict__ fc2w, const float* __restrict__ fc2b,
    const float* __restrict__ fc3w, const float* __restrict__ fc3b,
    float* __restrict__ out)
{
  __shared__ float m[64][77];
  __shared__ float a1[64][33];
  __shared__ float a2[64][17];
  int t = threadIdx.x;
  int g = blockIdx.x * 64 + t;
  bool ok = g < Gg;
  float c = ok ? fmaxf(cnts[g], 1.f) : 1.f;
  for (int f = 0; f < 75; ++f) m[t][f] = ok ? sums[(size_t)g * 75 + f] / c : 0.f;
  for (int j = 0; j < 32; ++j){
    float s = fc1b[j];
    for (int f = 0; f < 75; ++f) s += m[t][f] * fc1w[f * 32 + j];
    a1[t][j] = eluf(s);
  }
  for (int j = 0; j < 16; ++j){
    float s = fc2b[j];
    for (int i = 0; i < 32; ++i) s += a1[t][i] * fc2w[i * 16 + j];
    a2[t][j] = eluf(s);
  }
  float s = fc3b[0];
  for (int i = 0; i < 16; ++i) s += a2[t][i] * fc3w[i];
  if (ok) out[g] = s;
}

extern "C" void kernel_launch(void* const* d_in, const int* in_sizes, int n_in,
                              void* d_out, int out_size, void* d_ws, size_t ws_size,
                              hipStream_t stream)
{
  (void)in_sizes; (void)n_in; (void)out_size; (void)ws_size;
  const float* x     = (const float*)d_in[0];
  const int*   ei    = (const int*)d_in[1];
  const float* ea    = (const float*)d_in[2];
  const int*   batch = (const int*)d_in[3];
  const float* cw1[3]   = {(const float*)d_in[4],  (const float*)d_in[10], (const float*)d_in[16]};
  const float* cb1[3]   = {(const float*)d_in[5],  (const float*)d_in[11], (const float*)d_in[17]};
  const float* cw2[3]   = {(const float*)d_in[6],  (const float*)d_in[12], (const float*)d_in[18]};
  const float* cb2[3]   = {(const float*)d_in[7],  (const float*)d_in[13], (const float*)d_in[19]};
  const float* croot[3] = {(const float*)d_in[8],  (const float*)d_in[14], (const float*)d_in[20]};
  const float* cbias[3] = {(const float*)d_in[9],  (const float*)d_in[15], (const float*)d_in[21]};
  const float* fc1w = (const float*)d_in[22];
  const float* fc1b = (const float*)d_in[23];
  const float* fc2w = (const float*)d_in[24];
  const float* fc2b = (const float*)d_in[25];
  const float* fc3w = (const float*)d_in[26];
  const float* fc3b = (const float*)d_in[27];
  float* out = (float*)d_out;

  float* ws   = (float*)d_ws;
  float* w2t  = ws;                       // 4096*128 = 524288 floats (max layer)
  float* h    = w2t + 4096 * 128;         // N*64
  float* agg  = h + (size_t)Nn * 64;      // N*64
  float* sums = agg + (size_t)Nn * 64;    // G*75
  float* cnts = sums + (size_t)Gg * 75;   // G  (contiguous with sums)

  const int* src = ei;
  const int* dst = ei + Ee;

  h0_kernel<<<(Nn * 5 + 255) / 256, 256, 0, stream>>>(x, h);

  // ---- layer 1: MI=5, MO=32 ----
  w2t_kernel<<<(160 * HID + 255) / 256, 256, 0, stream>>>(cw2[0], w2t, 160);
  node_kernel<5, 32><<<(Nn * 32 + 255) / 256, 256, 0, stream>>>(h, croot[0], cbias[0], agg);
  edge_kernel<5, 32><<<Ee / 64, 256, 0, stream>>>(ea, cw1[0], cb1[0], w2t, cb2[0], h, src, dst, agg);
  elu_kernel<<<(Nn * 32 + 255) / 256, 256, 0, stream>>>(agg, h, Nn * 32);

  // ---- layer 2: MI=32, MO=64 ----
  w2t_kernel<<<(2048 * HID + 255) / 256, 256, 0, stream>>>(cw2[1], w2t, 2048);
  node_kernel<32, 64><<<(Nn * 64 + 255) / 256, 256, 0, stream>>>(h, croot[1], cbias[1], agg);
  edge_kernel<32, 64><<<Ee / 64, 256, 0, stream>>>(ea, cw1[1], cb1[1], w2t, cb2[1], h, src, dst, agg);
  elu_kernel<<<(Nn * 64 + 255) / 256, 256, 0, stream>>>(agg, h, Nn * 64);

  // ---- layer 3: MI=64, MO=64 ----
  w2t_kernel<<<(4096 * HID + 255) / 256, 256, 0, stream>>>(cw2[2], w2t, 4096);
  node_kernel<64, 64><<<(Nn * 64 + 255) / 256, 256, 0, stream>>>(h, croot[2], cbias[2], agg);
  edge_kernel<64, 64><<<Ee / 64, 256, 0, stream>>>(ea, cw1[2], cb1[2], w2t, cb2[2], h, src, dst, agg);
  elu_kernel<<<(Nn * 64 + 255) / 256, 256, 0, stream>>>(agg, h, Nn * 64);

  // ---- pooling + head ----
  zero_kernel<<<(Gg * 76 + 255) / 256, 256, 0, stream>>>(sums, Gg * 76);
  pool_kernel<<<(Nn * 75 + 255) / 256, 256, 0, stream>>>(h, x, batch, sums, cnts);
  head_kernel<<<(Gg + 63) / 64, 64, 0, stream>>>(sums, cnts, fc1w, fc1b, fc2w, fc2b, fc3w, fc3b, out);
}

// Round 2
// 580.444 us; speedup vs baseline: 6.4420x; 6.4420x over previous
//
#include <hip/hip_runtime.h>
#include <math.h>

#define HID 128
constexpr int Nn = 20000;
constexpr int Ee = 80000;
constexpr int Gg = 1000;

typedef _Float16 f16x8 __attribute__((ext_vector_type(8)));
typedef float    f32x4 __attribute__((ext_vector_type(4)));

__device__ __forceinline__ float eluf(float x){ return x > 0.f ? x : (expf(x) - 1.f); }

// h0 = x[:, :5]
__global__ void h0_kernel(const float* __restrict__ x, float* __restrict__ h){
  int idx = blockIdx.x * blockDim.x + threadIdx.x;
  if (idx >= Nn * 5) return;
  int n = idx / 5, c = idx - n * 5;
  h[idx] = x[(size_t)n * 16 + c];
}

// fp32 transpose for layer-1 edge kernel
__global__ void w2t_kernel(const float* __restrict__ w2, float* __restrict__ w2t, int iotot){
  int idx = blockIdx.x * blockDim.x + threadIdx.x;
  if (idx >= iotot * HID) return;
  int io = idx >> 7, k = idx & 127;
  w2t[idx] = w2[(size_t)k * iotot + io];
}

// ---- B permute for MFMA edge GEMM ----
// K-index kk = k*MI + i, K' = 129*MI (row k=128 carries b2).
// Fragment order: bt[((n*KS + ks)*64 + lane)*8 + j] = B[ks*32 + (lane>>4)*8 + j][n*16 + (lane&15)]
template<int MI>
__global__ void bt_kernel(const float* __restrict__ w2, const float* __restrict__ b2,
                          _Float16* __restrict__ bt){
  constexpr int KS = (129 * MI) / 32;
  int idx = blockIdx.x * 256 + threadIdx.x;
  if (idx >= 4 * KS * 512) return;
  int j  = idx & 7;
  int l  = (idx >> 3) & 63;
  int ks = (idx >> 9) % KS;
  int n  = idx / (KS * 512);
  int col = n * 16 + (l & 15);
  int kk  = ks * 32 + ((l >> 4) << 3) + j;
  int k = kk / MI, i = kk % MI;
  float v = (k < 128) ? w2[(size_t)k * (MI * 64) + i * 64 + col] : b2[i * 64 + col];
  bt[idx] = (_Float16)v;
}

// agg[n,o] = bias[o] + sum_i h[n,i]*root[i,o]
template<int MI, int MO>
__global__ void node_kernel(const float* __restrict__ h, const float* __restrict__ root,
                            const float* __restrict__ bias, float* __restrict__ agg){
  int idx = blockIdx.x * blockDim.x + threadIdx.x;
  if (idx >= Nn * MO) return;
  int n = idx / MO, o = idx - n * MO;
  float s = bias[o];
  #pragma unroll
  for (int i = 0; i < MI; ++i) s += h[(size_t)n * MI + i] * root[i * MO + o];
  agg[idx] = s;
}

// ---- MFMA edge kernel (MO=64): 2 waves, 64 edges/WG, each wave 32 edges x 64 cols ----
template<int MI>
__global__ __launch_bounds__(128) void edge_mfma(
    const float* __restrict__ ea, const float* __restrict__ w1, const float* __restrict__ b1,
    const _Float16* __restrict__ bt, const float* __restrict__ h,
    const int* __restrict__ src, const int* __restrict__ dst, float* __restrict__ agg)
{
  constexpr int KS   = (129 * MI) / 32;
  constexpr int L2MI = (MI == 64) ? 6 : 5;
  constexpr int HP   = MI + 8;            // 144B / 80B rows: 16B-aligned, 2-way banks

  __shared__ _Float16 hs_lds[64][HP];
  __shared__ _Float16 hid_lds[64][132];
  __shared__ float ea_lds[64][5];
  __shared__ float w1_lds[5][128];
  __shared__ float b1_lds[128];
  __shared__ int   src_l[64];
  __shared__ int   dst_l[64];

  const int tid  = threadIdx.x;
  const int lane = tid & 63;
  const int wave = tid >> 6;
  const int c15  = lane & 15;
  const int g    = lane >> 4;
  const int e0   = blockIdx.x * 64;

  // phase 0: stage small stuff
  for (int t = tid; t < 640; t += 128) w1_lds[t >> 7][t & 127] = w1[t];
  if (tid < 128) b1_lds[tid] = b1[tid];
  for (int t = tid; t < 320; t += 128) ea_lds[t / 5][t % 5] = ea[(size_t)e0 * 5 + t];
  if (tid < 64){ src_l[tid] = src[e0 + tid]; dst_l[tid] = dst[e0 + tid]; }
  __syncthreads();

  // phase 1: hid = relu(ea@w1+b1) (f16), hid[:,128]=1 ; gather h_src (f16)
  for (int t = tid; t < 64 * 129; t += 128){
    int e = t / 129, k = t - e * 129;
    float s;
    if (k < 128){
      s = b1_lds[k];
      #pragma unroll
      for (int j = 0; j < 5; ++j) s += ea_lds[e][j] * w1_lds[j][k];
      s = fmaxf(s, 0.f);
    } else s = 1.f;
    hid_lds[e][k] = (_Float16)s;
  }
  for (int t = tid; t < 64 * MI; t += 128){
    int e = t >> L2MI, i = t & (MI - 1);
    hs_lds[e][i] = (_Float16)h[(size_t)src_l[e] * MI + i];
  }
  __syncthreads();

  // main K loop: A built in registers, B streamed from L2 (fragment-ordered)
  const f16x8* __restrict__ btv = (const f16x8*)bt;
  f32x4 acc[2][4];
  #pragma unroll
  for (int m = 0; m < 2; ++m)
    #pragma unroll
    for (int n = 0; n < 4; ++n) acc[m][n] = (f32x4){0.f, 0.f, 0.f, 0.f};

  f16x8 bcur[4];
  #pragma unroll
  for (int n = 0; n < 4; ++n) bcur[n] = btv[(n * KS + 0) * 64 + lane];

  for (int ks = 0; ks < KS; ++ks){
    int ks2 = (ks + 1 < KS) ? ks + 1 : 0;
    f16x8 bnxt[4];
    #pragma unroll
    for (int n = 0; n < 4; ++n) bnxt[n] = btv[(n * KS + ks2) * 64 + lane];

    const int k    = (ks * 32) >> L2MI;
    const int ioff = (ks * 32 & (MI - 1)) + (g << 3);
    #pragma unroll
    for (int m = 0; m < 2; ++m){
      int er = ((wave << 1) + m) * 16 + c15;
      _Float16 hv = hid_lds[er][k];
      f16x8 hs8 = *(const f16x8*)&hs_lds[er][ioff];
      f16x8 hvv = {hv, hv, hv, hv, hv, hv, hv, hv};
      f16x8 av  = hs8 * hvv;
      #pragma unroll
      for (int n = 0; n < 4; ++n)
        acc[m][n] = __builtin_amdgcn_mfma_f32_16x16x32_f16(av, bcur[n], acc[m][n], 0, 0, 0);
    }
    #pragma unroll
    for (int n = 0; n < 4; ++n) bcur[n] = bnxt[n];
  }

  // epilogue: C row = (lane>>4)*4+j, col = lane&15
  #pragma unroll
  for (int m = 0; m < 2; ++m)
    #pragma unroll
    for (int n = 0; n < 4; ++n)
      #pragma unroll
      for (int j = 0; j < 4; ++j){
        int er = ((wave << 1) + m) * 16 + (g << 2) + j;
        atomicAdd(&agg[(size_t)dst_l[er] * 64 + n * 16 + c15], acc[m][n][j]);
      }
}

// fp32 edge kernel (layer 1 only)
template<int MI, int MO>
__global__ __launch_bounds__(256) void edge_kernel(
    const float* __restrict__ ea, const float* __restrict__ w1, const float* __restrict__ b1,
    const float* __restrict__ w2t, const float* __restrict__ b2,
    const float* __restrict__ h, const int* __restrict__ src, const int* __restrict__ dst,
    float* __restrict__ agg)
{
  constexpr int TE = 64;
  constexpr int OW = MO / 4;
  __shared__ float ea_lds[TE * 5];
  __shared__ __align__(16) float hid_lds[TE][132];
  __shared__ float hs_lds[TE][MI + 1];

  const int tid  = threadIdx.x;
  const int lane = tid & 63;
  const int wave = tid >> 6;
  const int e0   = blockIdx.x * TE;

  for (int t = tid; t < TE * 5; t += 256) ea_lds[t] = ea[(size_t)e0 * 5 + t];
  for (int t = tid; t < TE * MI; t += 256){
    int le = t / MI, i = t - le * MI;
    hs_lds[le][i] = h[(size_t)src[e0 + le] * MI + i];
  }
  __syncthreads();
  for (int t = tid; t < TE * HID; t += 256){
    int le = t >> 7, k = t & 127;
    float s = b1[k];
    #pragma unroll
    for (int j = 0; j < 5; ++j) s += ea_lds[le * 5 + j] * w1[j * HID + k];
    hid_lds[le][k] = fmaxf(s, 0.f);
  }
  __syncthreads();

  const int e  = e0 + lane;
  const int O0 = __builtin_amdgcn_readfirstlane(wave * OW);
  const int d  = dst[e];
  const float4* __restrict__ w2t4 = (const float4*)w2t;

  float acc[OW];
  #pragma unroll
  for (int ow = 0; ow < OW; ++ow) acc[ow] = 0.f;

  for (int i = 0; i < MI; ++i){
    float hs = hs_lds[lane][i];
    #pragma unroll
    for (int ow = 0; ow < OW; ++ow) acc[ow] += hs * b2[i * MO + O0 + ow];
  }
  for (int kb = 0; kb < HID / 4; ++kb){
    float4 hv = *(const float4*)&hid_lds[lane][kb * 4];
    for (int i = 0; i < MI; ++i){
      float hs  = hs_lds[lane][i];
      float hwx = hs * hv.x, hwy = hs * hv.y, hwz = hs * hv.z, hww = hs * hv.w;
      #pragma unroll
      for (int ow = 0; ow < OW; ++ow){
        float4 wv = w2t4[(size_t)(i * MO + O0 + ow) * (HID / 4) + kb];
        acc[ow] += hwx * wv.x + hwy * wv.y + hwz * wv.z + hww * wv.w;
      }
    }
  }
  #pragma unroll
  for (int ow = 0; ow < OW; ++ow)
    atomicAdd(&agg[(size_t)d * MO + O0 + ow], acc[ow]);
}

__global__ void elu_kernel(const float* __restrict__ agg, float* __restrict__ h, int n){
  int i = blockIdx.x * blockDim.x + threadIdx.x;
  if (i < n) h[i] = eluf(agg[i]);
}

__global__ void zero_kernel(float* __restrict__ p, int n){
  int i = blockIdx.x * blockDim.x + threadIdx.x;
  if (i < n) p[i] = 0.f;
}

__global__ void pool_kernel(const float* __restrict__ h, const float* __restrict__ x,
                            const int* __restrict__ batch,
                            float* __restrict__ sums, float* __restrict__ cnts){
  int idx = blockIdx.x * blockDim.x + threadIdx.x;
  if (idx >= Nn * 75) return;
  int n = idx / 75, f = idx - n * 75;
  float v = (f < 64) ? h[(size_t)n * 64 + f] : x[(size_t)n * 16 + 5 + (f - 64)];
  int b = batch[n];
  atomicAdd(&sums[(size_t)b * 75 + f], v);
  if (f == 0) atomicAdd(&cnts[b], 1.f);
}

__global__ __launch_bounds__(64) void head_kernel(
    const float* __restrict__ sums, const float* __restrict__ cnts,
    const float* __restrict__ fc1w, const float* __restrict__ fc1b,
    const float* __restrict__ fc2w, const float* __restrict__ fc2b,
    const float* __restrict__ fc3w, const float* __restrict__ fc3b,
    float* __restrict__ out)
{
  __shared__ float m[64][77];
  __shared__ float a1[64][33];
  __shared__ float a2[64][17];
  int t = threadIdx.x;
  int g = blockIdx.x * 64 + t;
  bool ok = g < Gg;
  float c = ok ? fmaxf(cnts[g], 1.f) : 1.f;
  for (int f = 0; f < 75; ++f) m[t][f] = ok ? sums[(size_t)g * 75 + f] / c : 0.f;
  for (int j = 0; j < 32; ++j){
    float s = fc1b[j];
    for (int f = 0; f < 75; ++f) s += m[t][f] * fc1w[f * 32 + j];
    a1[t][j] = eluf(s);
  }
  for (int j = 0; j < 16; ++j){
    float s = fc2b[j];
    for (int i = 0; i < 32; ++i) s += a1[t][i] * fc2w[i * 16 + j];
    a2[t][j] = eluf(s);
  }
  float s = fc3b[0];
  for (int i = 0; i < 16; ++i) s += a2[t][i] * fc3w[i];
  if (ok) out[g] = s;
}

extern "C" void kernel_launch(void* const* d_in, const int* in_sizes, int n_in,
                              void* d_out, int out_size, void* d_ws, size_t ws_size,
                              hipStream_t stream)
{
  (void)in_sizes; (void)n_in; (void)out_size; (void)ws_size;
  const float* x     = (const float*)d_in[0];
  const int*   ei    = (const int*)d_in[1];
  const float* ea    = (const float*)d_in[2];
  const int*   batch = (const int*)d_in[3];
  const float* cw1[3]   = {(const float*)d_in[4],  (const float*)d_in[10], (const float*)d_in[16]};
  const float* cb1[3]   = {(const float*)d_in[5],  (const float*)d_in[11], (const float*)d_in[17]};
  const float* cw2[3]   = {(const float*)d_in[6],  (const float*)d_in[12], (const float*)d_in[18]};
  const float* cb2[3]   = {(const float*)d_in[7],  (const float*)d_in[13], (const float*)d_in[19]};
  const float* croot[3] = {(const float*)d_in[8],  (const float*)d_in[14], (const float*)d_in[20]};
  const float* cbias[3] = {(const float*)d_in[9],  (const float*)d_in[15], (const float*)d_in[21]};
  const float* fc1w = (const float*)d_in[22];
  const float* fc1b = (const float*)d_in[23];
  const float* fc2w = (const float*)d_in[24];
  const float* fc2b = (const float*)d_in[25];
  const float* fc3w = (const float*)d_in[26];
  const float* fc3b = (const float*)d_in[27];
  float* out = (float*)d_out;

  float* ws   = (float*)d_ws;
  float* w2t  = ws;                              // 160*128 = 20480 f32
  float* h    = w2t + 20480;                     // N*64
  float* agg  = h + (size_t)Nn * 64;             // N*64
  float* sums = agg + (size_t)Nn * 64;           // G*75
  float* cnts = sums + (size_t)Gg * 75;          // G
  _Float16* bt2 = (_Float16*)(cnts + Gg);        // 64*4128 = 264192 f16
  _Float16* bt3 = bt2 + 264192;                  // 64*8256 = 528384 f16

  const int* src = ei;
  const int* dst = ei + Ee;

  h0_kernel<<<(Nn * 5 + 255) / 256, 256, 0, stream>>>(x, h);
  bt_kernel<32><<<(4 * 129 * 512 + 255) / 256, 256, 0, stream>>>(cw2[1], cb2[1], bt2);
  bt_kernel<64><<<(4 * 258 * 512 + 255) / 256, 256, 0, stream>>>(cw2[2], cb2[2], bt3);

  // ---- layer 1: MI=5, MO=32 (fp32 path) ----
  w2t_kernel<<<(160 * HID + 255) / 256, 256, 0, stream>>>(cw2[0], w2t, 160);
  node_kernel<5, 32><<<(Nn * 32 + 255) / 256, 256, 0, stream>>>(h, croot[0], cbias[0], agg);
  edge_kernel<5, 32><<<Ee / 64, 256, 0, stream>>>(ea, cw1[0], cb1[0], w2t, cb2[0], h, src, dst, agg);
  elu_kernel<<<(Nn * 32 + 255) / 256, 256, 0, stream>>>(agg, h, Nn * 32);

  // ---- layer 2: MI=32, MO=64 (MFMA) ----
  node_kernel<32, 64><<<(Nn * 64 + 255) / 256, 256, 0, stream>>>(h, croot[1], cbias[1], agg);
  edge_mfma<32><<<Ee / 64, 128, 0, stream>>>(ea, cw1[1], cb1[1], bt2, h, src, dst, agg);
  elu_kernel<<<(Nn * 64 + 255) / 256, 256, 0, stream>>>(agg, h, Nn * 64);

  // ---- layer 3: MI=64, MO=64 (MFMA) ----
  node_kernel<64, 64><<<(Nn * 64 + 255) / 256, 256, 0, stream>>>(h, croot[2], cbias[2], agg);
  edge_mfma<64><<<Ee / 64, 128, 0, stream>>>(ea, cw1[2], cb1[2], bt3, h, src, dst, agg);
  elu_kernel<<<(Nn * 64 + 255) / 256, 256, 0, stream>>>(agg, h, Nn * 64);

  // ---- pooling + head ----
  zero_kernel<<<(Gg * 76 + 255) / 256, 256, 0, stream>>>(sums, Gg * 76);
  pool_kernel<<<(Nn * 75 + 255) / 256, 256, 0, stream>>>(h, x, batch, sums, cnts);
  head_kernel<<<(Gg + 63) / 64, 64, 0, stream>>>(sums, cnts, fc1w, fc1b, fc2w, fc2b, fc3w, fc3b, out);
}

// Round 3
// 370.236 us; speedup vs baseline: 10.0996x; 1.5678x over previous
//
#include <hip/hip_runtime.h>
#include <math.h>

#define HID 128
constexpr int Nn = 20000;
constexpr int Ee = 80000;
constexpr int Gg = 1000;

typedef _Float16 f16x8 __attribute__((ext_vector_type(8)));
typedef float    f32x4 __attribute__((ext_vector_type(4)));

__device__ __forceinline__ float eluf(float x){ return x > 0.f ? x : (expf(x) - 1.f); }

// h0 = x[:, :5]
__global__ void h0_kernel(const float* __restrict__ x, float* __restrict__ h){
  int idx = blockIdx.x * blockDim.x + threadIdx.x;
  if (idx >= Nn * 5) return;
  int n = idx / 5, c = idx - n * 5;
  h[idx] = x[(size_t)n * 16 + c];
}

// ---- B permute for MFMA edge GEMM ----
// K-index kk = k*MIP + i, k < HIDK (row 128 carries b2, rows >128 are zero pad).
// Fragment order: bt[((n*KS+ks)*64 + l)*8 + j] = B[ks*32 + (l>>4)*8 + j][n*16 + (l&15)]
template<int MIR, int MIP, int MO, int HIDK>
__global__ void bt_kernel(const float* __restrict__ w2, const float* __restrict__ b2,
                          _Float16* __restrict__ bt){
  constexpr int KS = (HIDK * MIP) / 32;
  constexpr int NF = MO / 16;
  int idx = blockIdx.x * 256 + threadIdx.x;
  if (idx >= NF * KS * 512) return;
  int j  = idx & 7;
  int l  = (idx >> 3) & 63;
  int ks = (idx >> 9) % KS;
  int n  = idx / (KS * 512);
  int col = n * 16 + (l & 15);
  int kk  = ks * 32 + ((l >> 4) << 3) + j;
  int k = kk / MIP, i = kk % MIP;
  float v = 0.f;
  if (i < MIR){
    if (k < 128)       v = w2[(size_t)k * (MIR * MO) + i * MO + col];
    else if (k == 128) v = b2[i * MO + col];
  }
  bt[idx] = (_Float16)v;
}

// agg[n,o] = bias[o] + sum_i h[n,i]*root[i,o]
template<int MI, int MO>
__global__ void node_kernel(const float* __restrict__ h, const float* __restrict__ root,
                            const float* __restrict__ bias, float* __restrict__ agg){
  int idx = blockIdx.x * blockDim.x + threadIdx.x;
  if (idx >= Nn * MO) return;
  int n = idx / MO, o = idx - n * MO;
  float s = bias[o];
  #pragma unroll
  for (int i = 0; i < MI; ++i) s += h[(size_t)n * MI + i] * root[i * MO + o];
  agg[idx] = s;
}

// ---- MFMA edge kernel: 2 waves, 64 edges/WG, each wave 32 edges x MO cols ----
template<int MIR, int MIP, int MO, int HIDK>
__global__ __launch_bounds__(128) void edge_mfma(
    const float* __restrict__ ea, const float* __restrict__ w1, const float* __restrict__ b1,
    const _Float16* __restrict__ bt, const float* __restrict__ h,
    const int* __restrict__ src, const int* __restrict__ dst, float* __restrict__ agg)
{
  constexpr int KS   = (HIDK * MIP) / 32;
  constexpr int NF   = MO / 16;
  constexpr int L2MI = (MIP == 64) ? 6 : ((MIP == 32) ? 5 : 3);
  constexpr int HP   = (MIP == 8) ? 8 : MIP + 8;

  __shared__ _Float16 hs_lds[64][HP];
  __shared__ _Float16 hid_lds[64][132];
  __shared__ float ea_lds[64][5];
  __shared__ float w1_lds[5][128];
  __shared__ float b1_lds[128];
  __shared__ int   src_l[64];
  __shared__ int   dst_l[64];

  const int tid  = threadIdx.x;
  const int lane = tid & 63;
  const int wave = tid >> 6;
  const int c15  = lane & 15;
  const int g    = lane >> 4;
  const int e0   = blockIdx.x * 64;

  // phase 0: stage small stuff
  for (int t = tid; t < 640; t += 128) w1_lds[t >> 7][t & 127] = w1[t];
  if (tid < 128) b1_lds[tid] = b1[tid];
  for (int t = tid; t < 320; t += 128) ea_lds[t / 5][t % 5] = ea[(size_t)e0 * 5 + t];
  if (tid < 64){ src_l[tid] = src[e0 + tid]; dst_l[tid] = dst[e0 + tid]; }
  __syncthreads();

  // phase 1: hid = relu(ea@w1+b1) (f16); hid[:,128]=1, hid[:,>128]=0; gather h_src (f16, zero-pad)
  for (int t = tid; t < 64 * HIDK; t += 128){
    int e = t / HIDK, k = t - e * HIDK;
    float s;
    if (k < 128){
      s = b1_lds[k];
      #pragma unroll
      for (int j = 0; j < 5; ++j) s += ea_lds[e][j] * w1_lds[j][k];
      s = fmaxf(s, 0.f);
    } else s = (k == 128) ? 1.f : 0.f;
    hid_lds[e][k] = (_Float16)s;
  }
  for (int t = tid; t < 64 * MIP; t += 128){
    int e = t >> L2MI, i = t & (MIP - 1);
    hs_lds[e][i] = (i < MIR) ? (_Float16)h[(size_t)src_l[e] * MIR + i] : (_Float16)0.f;
  }
  __syncthreads();

  // main K loop: A built in registers, B streamed from L2 (fragment-ordered)
  const f16x8* __restrict__ btv = (const f16x8*)bt;
  f32x4 acc[2][NF];
  #pragma unroll
  for (int m = 0; m < 2; ++m)
    #pragma unroll
    for (int n = 0; n < NF; ++n) acc[m][n] = (f32x4){0.f, 0.f, 0.f, 0.f};

  f16x8 hs8_hoist[2];
  if constexpr (MIP == 8){
    #pragma unroll
    for (int m = 0; m < 2; ++m){
      int er = ((wave << 1) + m) * 16 + c15;
      hs8_hoist[m] = *(const f16x8*)&hs_lds[er][0];
    }
  }

  f16x8 bcur[NF];
  #pragma unroll
  for (int n = 0; n < NF; ++n) bcur[n] = btv[(n * KS + 0) * 64 + lane];

  for (int ks = 0; ks < KS; ++ks){
    int ks2 = (ks + 1 < KS) ? ks + 1 : 0;
    f16x8 bnxt[NF];
    #pragma unroll
    for (int n = 0; n < NF; ++n) bnxt[n] = btv[(n * KS + ks2) * 64 + lane];

    #pragma unroll
    for (int m = 0; m < 2; ++m){
      int er = ((wave << 1) + m) * 16 + c15;
      _Float16 hv;
      f16x8 hs8;
      if constexpr (MIP == 8){
        hv  = hid_lds[er][(ks << 2) + g];
        hs8 = hs8_hoist[m];
      } else {
        hv  = hid_lds[er][(ks * 32) >> L2MI];
        hs8 = *(const f16x8*)&hs_lds[er][(ks * 32 & (MIP - 1)) + (g << 3)];
      }
      f16x8 hvv = {hv, hv, hv, hv, hv, hv, hv, hv};
      f16x8 av  = hs8 * hvv;
      #pragma unroll
      for (int n = 0; n < NF; ++n)
        acc[m][n] = __builtin_amdgcn_mfma_f32_16x16x32_f16(av, bcur[n], acc[m][n], 0, 0, 0);
    }
    #pragma unroll
    for (int n = 0; n < NF; ++n) bcur[n] = bnxt[n];
  }

  // epilogue: C row = (lane>>4)*4+j, col = lane&15
  #pragma unroll
  for (int m = 0; m < 2; ++m)
    #pragma unroll
    for (int n = 0; n < NF; ++n)
      #pragma unroll
      for (int j = 0; j < 4; ++j){
        int er = ((wave << 1) + m) * 16 + (g << 2) + j;
        atomicAdd(&agg[(size_t)dst_l[er] * MO + n * 16 + c15], acc[m][n][j]);
      }
}

__global__ void elu_kernel(const float* __restrict__ agg, float* __restrict__ h, int n){
  int i = blockIdx.x * blockDim.x + threadIdx.x;
  if (i < n) h[i] = eluf(agg[i]);
}

__global__ void zero_kernel(float* __restrict__ p, int n){
  int i = blockIdx.x * blockDim.x + threadIdx.x;
  if (i < n) p[i] = 0.f;
}

__global__ void pool_kernel(const float* __restrict__ h, const float* __restrict__ x,
                            const int* __restrict__ batch,
                            float* __restrict__ sums, float* __restrict__ cnts){
  int idx = blockIdx.x * blockDim.x + threadIdx.x;
  if (idx >= Nn * 75) return;
  int n = idx / 75, f = idx - n * 75;
  float v = (f < 64) ? h[(size_t)n * 64 + f] : x[(size_t)n * 16 + 5 + (f - 64)];
  int b = batch[n];
  atomicAdd(&sums[(size_t)b * 75 + f], v);
  if (f == 0) atomicAdd(&cnts[b], 1.f);
}

__global__ __launch_bounds__(64) void head_kernel(
    const float* __restrict__ sums, const float* __restrict__ cnts,
    const float* __restrict__ fc1w, const float* __restrict__ fc1b,
    const float* __restrict__ fc2w, const float* __restrict__ fc2b,
    const float* __restrict__ fc3w, const float* __restrict__ fc3b,
    float* __restrict__ out)
{
  __shared__ float m[64][77];
  __shared__ float a1[64][33];
  __shared__ float a2[64][17];
  int t = threadIdx.x;
  int g = blockIdx.x * 64 + t;
  bool ok = g < Gg;
  float c = ok ? fmaxf(cnts[g], 1.f) : 1.f;
  for (int f = 0; f < 75; ++f) m[t][f] = ok ? sums[(size_t)g * 75 + f] / c : 0.f;
  for (int j = 0; j < 32; ++j){
    float s = fc1b[j];
    for (int f = 0; f < 75; ++f) s += m[t][f] * fc1w[f * 32 + j];
    a1[t][j] = eluf(s);
  }
  for (int j = 0; j < 16; ++j){
    float s = fc2b[j];
    for (int i = 0; i < 32; ++i) s += a1[t][i] * fc2w[i * 16 + j];
    a2[t][j] = eluf(s);
  }
  float s = fc3b[0];
  for (int i = 0; i < 16; ++i) s += a2[t][i] * fc3w[i];
  if (ok) out[g] = s;
}

extern "C" void kernel_launch(void* const* d_in, const int* in_sizes, int n_in,
                              void* d_out, int out_size, void* d_ws, size_t ws_size,
                              hipStream_t stream)
{
  (void)in_sizes; (void)n_in; (void)out_size; (void)ws_size;
  const float* x     = (const float*)d_in[0];
  const int*   ei    = (const int*)d_in[1];
  const float* ea    = (const float*)d_in[2];
  const int*   batch = (const int*)d_in[3];
  const float* cw1[3]   = {(const float*)d_in[4],  (const float*)d_in[10], (const float*)d_in[16]};
  const float* cb1[3]   = {(const float*)d_in[5],  (const float*)d_in[11], (const float*)d_in[17]};
  const float* cw2[3]   = {(const float*)d_in[6],  (const float*)d_in[12], (const float*)d_in[18]};
  const float* cb2[3]   = {(const float*)d_in[7],  (const float*)d_in[13], (const float*)d_in[19]};
  const float* croot[3] = {(const float*)d_in[8],  (const float*)d_in[14], (const float*)d_in[20]};
  const float* cbias[3] = {(const float*)d_in[9],  (const float*)d_in[15], (const float*)d_in[21]};
  const float* fc1w = (const float*)d_in[22];
  const float* fc1b = (const float*)d_in[23];
  const float* fc2w = (const float*)d_in[24];
  const float* fc2b = (const float*)d_in[25];
  const float* fc3w = (const float*)d_in[26];
  const float* fc3b = (const float*)d_in[27];
  float* out = (float*)d_out;

  float* ws   = (float*)d_ws;
  float* h    = ws;                              // N*64
  float* agg  = h + (size_t)Nn * 64;             // N*64
  float* sums = agg + (size_t)Nn * 64;           // G*75
  float* cnts = sums + (size_t)Gg * 75;          // G
  _Float16* bt1 = (_Float16*)(cnts + Gg);        // 2*33*512  = 33792 f16
  _Float16* bt2 = bt1 + 33792;                   // 4*129*512 = 264192 f16
  _Float16* bt3 = bt2 + 264192;                  // 4*258*512 = 528384 f16

  const int* src = ei;
  const int* dst = ei + Ee;

  h0_kernel<<<(Nn * 5 + 255) / 256, 256, 0, stream>>>(x, h);
  bt_kernel<5, 8, 32, 132><<<(2 * 33 * 512 + 255) / 256, 256, 0, stream>>>(cw2[0], cb2[0], bt1);
  bt_kernel<32, 32, 64, 129><<<(4 * 129 * 512 + 255) / 256, 256, 0, stream>>>(cw2[1], cb2[1], bt2);
  bt_kernel<64, 64, 64, 129><<<(4 * 258 * 512 + 255) / 256, 256, 0, stream>>>(cw2[2], cb2[2], bt3);

  // ---- layer 1: MI=5 (pad 8), MO=32 (MFMA) ----
  node_kernel<5, 32><<<(Nn * 32 + 255) / 256, 256, 0, stream>>>(h, croot[0], cbias[0], agg);
  edge_mfma<5, 8, 32, 132><<<Ee / 64, 128, 0, stream>>>(ea, cw1[0], cb1[0], bt1, h, src, dst, agg);
  elu_kernel<<<(Nn * 32 + 255) / 256, 256, 0, stream>>>(agg, h, Nn * 32);

  // ---- layer 2: MI=32, MO=64 (MFMA) ----
  node_kernel<32, 64><<<(Nn * 64 + 255) / 256, 256, 0, stream>>>(h, croot[1], cbias[1], agg);
  edge_mfma<32, 32, 64, 129><<<Ee / 64, 128, 0, stream>>>(ea, cw1[1], cb1[1], bt2, h, src, dst, agg);
  elu_kernel<<<(Nn * 64 + 255) / 256, 256, 0, stream>>>(agg, h, Nn * 64);

  // ---- layer 3: MI=64, MO=64 (MFMA) ----
  node_kernel<64, 64><<<(Nn * 64 + 255) / 256, 256, 0, stream>>>(h, croot[2], cbias[2], agg);
  edge_mfma<64, 64, 64, 129><<<Ee / 64, 128, 0, stream>>>(ea, cw1[2], cb1[2], bt3, h, src, dst, agg);
  elu_kernel<<<(Nn * 64 + 255) / 256, 256, 0, stream>>>(agg, h, Nn * 64);

  // ---- pooling + head ----
  zero_kernel<<<(Gg * 76 + 255) / 256, 256, 0, stream>>>(sums, Gg * 76);
  pool_kernel<<<(Nn * 75 + 255) / 256, 256, 0, stream>>>(h, x, batch, sums, cnts);
  head_kernel<<<(Gg + 63) / 64, 64, 0, stream>>>(sums, cnts, fc1w, fc1b, fc2w, fc2b, fc3w, fc3b, out);
}

// Round 4
// 328.861 us; speedup vs baseline: 11.3703x; 1.1258x over previous
//
#include <hip/hip_runtime.h>
#include <math.h>

#define HID 128
constexpr int Nn = 20000;
constexpr int Ee = 80000;
constexpr int Gg = 1000;

typedef _Float16 f16x8 __attribute__((ext_vector_type(8)));
typedef _Float16 f16x4 __attribute__((ext_vector_type(4)));
typedef _Float16 f16x2 __attribute__((ext_vector_type(2)));
typedef float    f32x4 __attribute__((ext_vector_type(4)));

__device__ __forceinline__ float eluf(float x){ return x > 0.f ? x : (expf(x) - 1.f); }

// h0 = x[:, :5]
__global__ void h0_kernel(const float* __restrict__ x, float* __restrict__ h){
  int idx = blockIdx.x * blockDim.x + threadIdx.x;
  if (idx >= Nn * 5) return;
  int n = idx / 5, c = idx - n * 5;
  h[idx] = x[(size_t)n * 16 + c];
}

// ---- B permute for MFMA edge GEMM (ks-major layout) ----
// bt[((ks*NF + n)*64 + l)*8 + j] = B[ks*32 + (l>>4)*8 + j][n*16 + (l&15)]
// kk = k*MIP + i ; k==128 carries b2 ; k>128 zero pad ; i>=MIR zero pad.
template<int MIR, int MIP, int MO, int HIDK>
__global__ void bt_kernel(const float* __restrict__ w2, const float* __restrict__ b2,
                          _Float16* __restrict__ bt){
  constexpr int KS = (HIDK * MIP) / 32;
  constexpr int NF = MO / 16;
  int idx = blockIdx.x * 256 + threadIdx.x;
  if (idx >= NF * KS * 512) return;
  int j  = idx & 7;
  int l  = (idx >> 3) & 63;
  int n  = (idx >> 9) % NF;
  int ks = idx / (NF * 512);
  int col = n * 16 + (l & 15);
  int kk  = ks * 32 + ((l >> 4) << 3) + j;
  int k = kk / MIP, i = kk % MIP;
  float v = 0.f;
  if (i < MIR){
    if (k < 128)       v = w2[(size_t)k * (MIR * MO) + i * MO + col];
    else if (k == 128) v = b2[i * MO + col];
  }
  bt[idx] = (_Float16)v;
}

// agg[n,o] = bias[o] + sum_i h[n,i]*root[i,o]
template<int MI, int MO>
__global__ void node_kernel(const float* __restrict__ h, const float* __restrict__ root,
                            const float* __restrict__ bias, float* __restrict__ agg){
  int idx = blockIdx.x * blockDim.x + threadIdx.x;
  if (idx >= Nn * MO) return;
  int n = idx / MO, o = idx - n * MO;
  float s = bias[o];
  #pragma unroll
  for (int i = 0; i < MI; ++i) s += h[(size_t)n * MI + i] * root[i * MO + o];
  agg[idx] = s;
}

// ---- MFMA edge kernel: 2 waves/WG, 64 edges/WG, wave = 32 edges x MO cols ----
// depth-4 B prefetch, A hoisted to registers, swizzled hs_lds.
template<int MIR, int MIP, int MO, int HIDK>
__global__ __launch_bounds__(128) void edge_mfma(
    const float* __restrict__ ea, const float* __restrict__ w1, const float* __restrict__ b1,
    const _Float16* __restrict__ bt, const float* __restrict__ h,
    const int* __restrict__ src, const int* __restrict__ dst, float* __restrict__ agg)
{
  constexpr int KS   = (HIDK * MIP) / 32;          // multiple of 4
  constexpr int NF   = MO / 16;
  constexpr int NBLK = MIP / 8;                    // 16B blocks per hs row
  constexpr int HIDP = (MIP == 8) ? 148 : ((HIDK + 3) & ~3);
  static_assert((KS & 3) == 0, "KS must be multiple of 4");

  __shared__ __align__(8)  _Float16 hid_lds[64][HIDP];
  __shared__ __align__(16) _Float16 hs_lds[64][MIP];   // XOR-swizzled 16B blocks
  __shared__ float ea_lds[64][5];
  __shared__ float w1_lds[5][128];
  __shared__ float b1_lds[128];
  __shared__ int   src_l[64];
  __shared__ int   dst_l[64];

  const int tid  = threadIdx.x;
  const int lane = tid & 63;
  const int wave = tid >> 6;
  const int c15  = lane & 15;
  const int g    = lane >> 4;
  const int e0   = blockIdx.x * 64;

  // phase 0: stage small stuff
  for (int t = tid; t < 640; t += 128) w1_lds[t >> 7][t & 127] = w1[t];
  if (tid < 128) b1_lds[tid] = b1[tid];
  for (int t = tid; t < 320; t += 128) ea_lds[t / 5][t % 5] = ea[(size_t)e0 * 5 + t];
  if (tid < 64){ src_l[tid] = src[e0 + tid]; dst_l[tid] = dst[e0 + tid]; }
  __syncthreads();

  // phase 1: hid = relu(ea@w1+b1) (f16); row 128 = 1 (bias), rows >128 = 0.
  for (int t = tid; t < 64 * HIDK; t += 128){
    int e = t / HIDK, k = t - e * HIDK;
    float s;
    if (k < 128){
      s = b1_lds[k];
      #pragma unroll
      for (int j = 0; j < 5; ++j) s += ea_lds[e][j] * w1_lds[j][k];
      s = fmaxf(s, 0.f);
    } else s = (k == 128) ? 1.f : 0.f;
    hid_lds[e][k] = (_Float16)s;
  }
  // gather h_src (f16, zero-pad i>=MIR), block-swizzled
  for (int t = tid; t < 64 * MIP; t += 128){
    int e = t / MIP, i = t - e * MIP;
    int bw = ((i >> 3) ^ (e & (NBLK - 1)));
    hs_lds[e][(bw << 3) | (i & 7)] =
        (i < MIR) ? (_Float16)h[(size_t)src_l[e] * MIR + i] : (_Float16)0.f;
  }
  __syncthreads();

  const f16x8* __restrict__ btv = (const f16x8*)bt;
  f32x4 acc[2][NF];
  #pragma unroll
  for (int m = 0; m < 2; ++m)
    #pragma unroll
    for (int n = 0; n < NF; ++n) acc[m][n] = (f32x4){0.f, 0.f, 0.f, 0.f};

  // A hoist: hs fragments live in registers for the whole K loop
  f16x8 hsh[2][2];
  #pragma unroll
  for (int m = 0; m < 2; ++m){
    const int er = ((wave << 1) + m) * 16 + c15;
    if constexpr (MIP == 8){
      hsh[m][0] = *(const f16x8*)&hs_lds[er][0];
      hsh[m][1] = hsh[m][0];
    } else if constexpr (MIP == 32){
      int blk = g ^ (er & 3);
      hsh[m][0] = *(const f16x8*)&hs_lds[er][blk << 3];
      hsh[m][1] = hsh[m][0];
    } else {
      int b0 = g ^ (er & 7), b1x = (4 + g) ^ (er & 7);
      hsh[m][0] = *(const f16x8*)&hs_lds[er][b0 << 3];
      hsh[m][1] = *(const f16x8*)&hs_lds[er][b1x << 3];
    }
  }

  // B prologue: 4 slots = ks 0..3
  f16x8 bq0[NF], bq1[NF], bq2[NF], bq3[NF];
  #pragma unroll
  for (int n = 0; n < NF; ++n){
    bq0[n] = btv[(size_t)(0 * NF + n) * 64 + lane];
    bq1[n] = btv[(size_t)(1 * NF + n) * 64 + lane];
    bq2[n] = btv[(size_t)(2 * NF + n) * 64 + lane];
    bq3[n] = btv[(size_t)(3 * NF + n) * 64 + lane];
  }

#define EDGE_SUB(U, BQ)                                                         \
  {                                                                             \
    _Pragma("unroll")                                                           \
    for (int m = 0; m < 2; ++m){                                                \
      _Float16 hv;                                                              \
      f16x8 hs8;                                                                \
      if constexpr (MIP == 64){ hv = hvp[m][(U) >> 1]; hs8 = hsh[m][(U) & 1]; } \
      else if constexpr (MIP == 32){ hv = hv4[m][(U)]; hs8 = hsh[m][0]; }       \
      else { hv = hid_lds[((wave << 1) + m) * 16 + c15][((ks0 + (U)) << 2) + g];\
             hs8 = hsh[m][0]; }                                                 \
      f16x8 hvv = {hv, hv, hv, hv, hv, hv, hv, hv};                             \
      f16x8 av  = hs8 * hvv;                                                    \
      _Pragma("unroll")                                                         \
      for (int n = 0; n < NF; ++n)                                              \
        acc[m][n] = __builtin_amdgcn_mfma_f32_16x16x32_f16(av, BQ[n],           \
                                                           acc[m][n], 0, 0, 0);\
    }                                                                           \
    _Pragma("unroll")                                                           \
    for (int n = 0; n < NF; ++n)                                                \
      BQ[n] = btv[(size_t)((ks0 + (U) + 4) * NF + n) * 64 + lane];              \
  }

  for (int ks0 = 0; ks0 < KS; ks0 += 4){
    f16x2 hvp[2]; f16x4 hv4[2];
    if constexpr (MIP == 64){
      #pragma unroll
      for (int m = 0; m < 2; ++m)
        hvp[m] = *(const f16x2*)&hid_lds[((wave << 1) + m) * 16 + c15][ks0 >> 1];
    } else if constexpr (MIP == 32){
      #pragma unroll
      for (int m = 0; m < 2; ++m)
        hv4[m] = *(const f16x4*)&hid_lds[((wave << 1) + m) * 16 + c15][ks0];
    }
    (void)hvp; (void)hv4;
    EDGE_SUB(0, bq0)
    EDGE_SUB(1, bq1)
    EDGE_SUB(2, bq2)
    EDGE_SUB(3, bq3)
  }
#undef EDGE_SUB

  // epilogue: C row = (lane>>4)*4+j, col = lane&15
  #pragma unroll
  for (int m = 0; m < 2; ++m)
    #pragma unroll
    for (int n = 0; n < NF; ++n)
      #pragma unroll
      for (int j = 0; j < 4; ++j){
        int er = ((wave << 1) + m) * 16 + (g << 2) + j;
        atomicAdd(&agg[(size_t)dst_l[er] * MO + n * 16 + c15], acc[m][n][j]);
      }
}

__global__ void elu_kernel(const float* __restrict__ agg, float* __restrict__ h, int n){
  int i = blockIdx.x * blockDim.x + threadIdx.x;
  if (i < n) h[i] = eluf(agg[i]);
}

__global__ void zero_kernel(float* __restrict__ p, int n){
  int i = blockIdx.x * blockDim.x + threadIdx.x;
  if (i < n) p[i] = 0.f;
}

__global__ void pool_kernel(const float* __restrict__ h, const float* __restrict__ x,
                            const int* __restrict__ batch,
                            float* __restrict__ sums, float* __restrict__ cnts){
  int idx = blockIdx.x * blockDim.x + threadIdx.x;
  if (idx >= Nn * 75) return;
  int n = idx / 75, f = idx - n * 75;
  float v = (f < 64) ? h[(size_t)n * 64 + f] : x[(size_t)n * 16 + 5 + (f - 64)];
  int b = batch[n];
  atomicAdd(&sums[(size_t)b * 75 + f], v);
  if (f == 0) atomicAdd(&cnts[b], 1.f);
}

__global__ __launch_bounds__(64) void head_kernel(
    const float* __restrict__ sums, const float* __restrict__ cnts,
    const float* __restrict__ fc1w, const float* __restrict__ fc1b,
    const float* __restrict__ fc2w, const float* __restrict__ fc2b,
    const float* __restrict__ fc3w, const float* __restrict__ fc3b,
    float* __restrict__ out)
{
  __shared__ float m[64][77];
  __shared__ float a1[64][33];
  __shared__ float a2[64][17];
  int t = threadIdx.x;
  int g = blockIdx.x * 64 + t;
  bool ok = g < Gg;
  float c = ok ? fmaxf(cnts[g], 1.f) : 1.f;
  for (int f = 0; f < 75; ++f) m[t][f] = ok ? sums[(size_t)g * 75 + f] / c : 0.f;
  for (int j = 0; j < 32; ++j){
    float s = fc1b[j];
    for (int f = 0; f < 75; ++f) s += m[t][f] * fc1w[f * 32 + j];
    a1[t][j] = eluf(s);
  }
  for (int j = 0; j < 16; ++j){
    float s = fc2b[j];
    for (int i = 0; i < 32; ++i) s += a1[t][i] * fc2w[i * 16 + j];
    a2[t][j] = eluf(s);
  }
  float s = fc3b[0];
  for (int i = 0; i < 16; ++i) s += a2[t][i] * fc3w[i];
  if (ok) out[g] = s;
}

extern "C" void kernel_launch(void* const* d_in, const int* in_sizes, int n_in,
                              void* d_out, int out_size, void* d_ws, size_t ws_size,
                              hipStream_t stream)
{
  (void)in_sizes; (void)n_in; (void)out_size; (void)ws_size;
  const float* x     = (const float*)d_in[0];
  const int*   ei    = (const int*)d_in[1];
  const float* ea    = (const float*)d_in[2];
  const int*   batch = (const int*)d_in[3];
  const float* cw1[3]   = {(const float*)d_in[4],  (const float*)d_in[10], (const float*)d_in[16]};
  const float* cb1[3]   = {(const float*)d_in[5],  (const float*)d_in[11], (const float*)d_in[17]};
  const float* cw2[3]   = {(const float*)d_in[6],  (const float*)d_in[12], (const float*)d_in[18]};
  const float* cb2[3]   = {(const float*)d_in[7],  (const float*)d_in[13], (const float*)d_in[19]};
  const float* croot[3] = {(const float*)d_in[8],  (const float*)d_in[14], (const float*)d_in[20]};
  const float* cbias[3] = {(const float*)d_in[9],  (const float*)d_in[15], (const float*)d_in[21]};
  const float* fc1w = (const float*)d_in[22];
  const float* fc1b = (const float*)d_in[23];
  const float* fc2w = (const float*)d_in[24];
  const float* fc2b = (const float*)d_in[25];
  const float* fc3w = (const float*)d_in[26];
  const float* fc3b = (const float*)d_in[27];
  float* out = (float*)d_out;

  float* ws   = (float*)d_ws;
  float* h    = ws;                              // N*64
  float* agg  = h + (size_t)Nn * 64;             // N*64
  float* sums = agg + (size_t)Nn * 64;           // G*75
  float* cnts = sums + (size_t)Gg * 75;          // G
  // bt arrays sized with +4 ks-slots of prefetch headroom
  _Float16* bt1 = (_Float16*)(cnts + Gg);        // 2*(36+4)*512  = 40960
  _Float16* bt2 = bt1 + 40960;                   // 4*(132+4)*512 = 278528
  _Float16* bt3 = bt2 + 278528;                  // 4*(260+4)*512 = 540672

  const int* src = ei;
  const int* dst = ei + Ee;

  h0_kernel<<<(Nn * 5 + 255) / 256, 256, 0, stream>>>(x, h);
  bt_kernel<5, 8, 32, 144><<<(2 * 36 * 512 + 255) / 256, 256, 0, stream>>>(cw2[0], cb2[0], bt1);
  bt_kernel<32, 32, 64, 132><<<(4 * 132 * 512 + 255) / 256, 256, 0, stream>>>(cw2[1], cb2[1], bt2);
  bt_kernel<64, 64, 64, 130><<<(4 * 260 * 512 + 255) / 256, 256, 0, stream>>>(cw2[2], cb2[2], bt3);

  // ---- layer 1: MI=5 (pad 8), MO=32 ----
  node_kernel<5, 32><<<(Nn * 32 + 255) / 256, 256, 0, stream>>>(h, croot[0], cbias[0], agg);
  edge_mfma<5, 8, 32, 144><<<Ee / 64, 128, 0, stream>>>(ea, cw1[0], cb1[0], bt1, h, src, dst, agg);
  elu_kernel<<<(Nn * 32 + 255) / 256, 256, 0, stream>>>(agg, h, Nn * 32);

  // ---- layer 2: MI=32, MO=64 ----
  node_kernel<32, 64><<<(Nn * 64 + 255) / 256, 256, 0, stream>>>(h, croot[1], cbias[1], agg);
  edge_mfma<32, 32, 64, 132><<<Ee / 64, 128, 0, stream>>>(ea, cw1[1], cb1[1], bt2, h, src, dst, agg);
  elu_kernel<<<(Nn * 64 + 255) / 256, 256, 0, stream>>>(agg, h, Nn * 64);

  // ---- layer 3: MI=64, MO=64 ----
  node_kernel<64, 64><<<(Nn * 64 + 255) / 256, 256, 0, stream>>>(h, croot[2], cbias[2], agg);
  edge_mfma<64, 64, 64, 130><<<Ee / 64, 128, 0, stream>>>(ea, cw1[2], cb1[2], bt3, h, src, dst, agg);
  elu_kernel<<<(Nn * 64 + 255) / 256, 256, 0, stream>>>(agg, h, Nn * 64);

  // ---- pooling + head ----
  zero_kernel<<<(Gg * 76 + 255) / 256, 256, 0, stream>>>(sums, Gg * 76);
  pool_kernel<<<(Nn * 75 + 255) / 256, 256, 0, stream>>>(h, x, batch, sums, cnts);
  head_kernel<<<(Gg + 63) / 64, 64, 0, stream>>>(sums, cnts, fc1w, fc1b, fc2w, fc2b, fc3w, fc3b, out);
}